// Round 11
// baseline (203.967 us; speedup 1.0000x reference)
//
#include <hip/hip_runtime.h>
#include <cstdint>
#include <cstddef>

// ---------------- problem constants ----------------
#define BATCH 16
#define NBOX 25200
#define NCH 85          // 4 box + 1 obj + 80 cls
#define KPRE 1024
#define MAXDET 1000
#define NCAND_MAX 4096
#define NCHUNK 99       // ceil(NBOX / 256)
#define IDX_PAD 0xFFFFFFFFu

__device__ __forceinline__ unsigned key_of(float s) {
    // monotone map: larger score -> SMALLER key (ascending sort = descending score)
    unsigned u = __float_as_uint(s);
    unsigned m = (u & 0x80000000u) ? ~u : (u | 0x80000000u);
    return ~m;
}

// ---------------- kernel 0: fast workspace zero ----------------
__global__ __launch_bounds__(256) void zero_kernel(uint4* __restrict__ p, int n16) {
    int i = blockIdx.x * 256 + threadIdx.x;
    if (i < n16) p[i] = make_uint4(0u, 0u, 0u, 0u);
}

// ---------------- kernel 1: per-box max-product score + key + histogram ----------------
// 256-thr block stages 64 rows (21.76KB) with contiguous float4 (minimal L1 transactions),
// one barrier, then 4 threads/box reduce 20 classes each from LDS (2-way banks = free).
__global__ __launch_bounds__(256) void score_kernel(const float* __restrict__ x,
                                                    unsigned* __restrict__ k32,
                                                    unsigned* __restrict__ hist,
                                                    int shift, int hs) {
    __shared__ __align__(16) float lds[64 * NCH];          // 21760 B -> 7 blocks/CU
    int t = threadIdx.x;
    int box0 = blockIdx.x * 64;

    // stage: 64*85 floats = 1360 float4, contiguous, 16B-aligned (64*85*4 % 16 == 0)
    const float4* src = (const float4*)(x + (size_t)box0 * NCH);
    float4* dst = (float4*)lds;
    #pragma unroll
    for (int it = 0; it < 6; it++) {
        int idx = t + it * 256;
        if (idx < (64 * NCH) / 4) dst[idx] = src[idx];
    }
    __syncthreads();

    int r = t >> 2;                     // box within tile [0,64)
    int q = t & 3;                      // quarter [0,4)
    const float* row = lds + r * NCH;
    float obj = row[4];                 // 4-lane broadcast, conflict-free
    float v = -1e30f;
    #pragma unroll
    for (int j = 0; j < 20; j++)        // bank = (21r+20q+5+j)%32 -> 2-way (free)
        v = fmaxf(v, row[5 + q * 20 + j] * obj);
    v = fmaxf(v, __shfl_xor(v, 1));     // max of products: order-invariant value
    v = fmaxf(v, __shfl_xor(v, 2));

    if (q == 0) {
        int box = box0 + r;
        bool validb = (obj > 0.25f) && (v > 0.25f);
        float score = validb ? v : -1.0f;
        unsigned k = key_of(score);
        k32[box] = k;
        if (validb) {
            int b = box / NBOX;
            atomicAdd(&hist[b * hs + (int)(k >> shift)], 1u);  // commutative -> deterministic
        }
    }
}

// ---------------- kernel 2: find histogram cutoff prefix covering rank KPRE ----------------
// uint4 reads (4x fewer load instructions over the 4MB hist)
__global__ __launch_bounds__(256) void select_cutoff(const unsigned* __restrict__ hist,
                                                     unsigned* __restrict__ cutoff, int hs) {
    int b = blockIdx.x, t = threadIdx.x;
    __shared__ unsigned part[256];
    const unsigned* h = hist + (size_t)b * hs;
    int perT = hs >> 8;                         // buckets per thread (contiguous)
    const uint4* h4 = (const uint4*)(h + t * perT);
    unsigned s = 0;
    for (int j = 0; j < perT / 4; j++) {
        uint4 vv = h4[j];
        s += vv.x + vv.y + vv.z + vv.w;
    }
    part[t] = s;
    __syncthreads();
    if (t == 0) {
        unsigned cum = 0;
        int chunk = 0;
        for (; chunk < 256; chunk++) {
            if (cum + part[chunk] >= KPRE) break;
            cum += part[chunk];
        }
        unsigned P = hs - 1;                    // fewer than KPRE valid -> take all valid
        if (chunk < 256) {
            int base = chunk * perT;
            for (int j = 0; j < perT; j++) {
                cum += h[base + j];
                if (cum >= KPRE) { P = base + j; break; }
            }
        }
        cutoff[b] = P;
    }
}

// ---------------- kernels 3a/3b/3c: DETERMINISTIC candidate compaction ----------------
__device__ __forceinline__ bool cand_pass(const unsigned* k32, const unsigned* cutoff,
                                          int b, int i, unsigned& k, int shift) {
    if (i >= NBOX) return false;
    k = k32[(size_t)b * NBOX + i];
    return ((int)k >= 0) && ((k >> shift) <= cutoff[b]);  // sign bit set = invalid
}

__global__ __launch_bounds__(256) void count_kernel(const unsigned* __restrict__ k32,
                                                    const unsigned* __restrict__ cutoff,
                                                    unsigned* __restrict__ chunkCnt, int shift) {
    int b = blockIdx.y, chunk = blockIdx.x;
    int i = chunk * 256 + threadIdx.x;
    unsigned k;
    bool pass = cand_pass(k32, cutoff, b, i, k, shift);
    unsigned long long m = __ballot(pass);
    __shared__ unsigned wc[4];
    int lane = threadIdx.x & 63, wid = threadIdx.x >> 6;
    if (lane == 0) wc[wid] = (unsigned)__popcll(m);
    __syncthreads();
    if (threadIdx.x == 0) chunkCnt[b * NCHUNK + chunk] = wc[0] + wc[1] + wc[2] + wc[3];
}

__global__ __launch_bounds__(128) void scan_kernel(unsigned* __restrict__ chunkCnt,
                                                   unsigned* __restrict__ ncand) {
    int b = blockIdx.x, t = threadIdx.x;
    __shared__ unsigned s[128];
    unsigned v = (t < NCHUNK) ? chunkCnt[b * NCHUNK + t] : 0u;
    s[t] = v;
    __syncthreads();
    #pragma unroll
    for (int off = 1; off < 128; off <<= 1) {
        unsigned u = (t >= off) ? s[t - off] : 0u;
        __syncthreads();
        s[t] += u;
        __syncthreads();
    }
    if (t < NCHUNK) chunkCnt[b * NCHUNK + t] = s[t] - v;   // exclusive
    if (t == NCHUNK - 1) ncand[b] = s[t];
}

__global__ __launch_bounds__(256) void place_kernel(const unsigned* __restrict__ k32,
                                                    const unsigned* __restrict__ cutoff,
                                                    const unsigned* __restrict__ chunkCnt,
                                                    unsigned long long* __restrict__ cand, int shift) {
    int b = blockIdx.y, chunk = blockIdx.x;
    int i = chunk * 256 + threadIdx.x;
    unsigned k = 0;
    bool pass = cand_pass(k32, cutoff, b, i, k, shift);
    unsigned long long m = __ballot(pass);
    __shared__ unsigned wc[4];
    int lane = threadIdx.x & 63, wid = threadIdx.x >> 6;
    if (lane == 0) wc[wid] = (unsigned)__popcll(m);
    __syncthreads();
    unsigned base = chunkCnt[b * NCHUNK + chunk];
    base += (wid > 0 ? wc[0] : 0u) + (wid > 1 ? wc[1] : 0u) + (wid > 2 ? wc[2] : 0u);
    unsigned rank = base + (unsigned)__popcll(lane ? (m & ((~0ull) >> (64 - lane))) : 0ull);
    if (pass && rank < NCAND_MAX)
        cand[(size_t)b * NCAND_MAX + rank] = ((unsigned long long)k << 32) | (unsigned)i;
}

// ---------------- kernel 4: bitonic sort candidates (dynamic size) -> topconf/topidx ----------------
__global__ __launch_bounds__(1024) void sort_gather(const unsigned long long* __restrict__ cand,
                                                    const unsigned* __restrict__ ncand,
                                                    float* __restrict__ topconf,
                                                    unsigned* __restrict__ topidx) {
    __shared__ unsigned long long keys[NCAND_MAX];
    int b = blockIdx.x, t = threadIdx.x;
    int n = (int)ncand[b];
    if (n > NCAND_MAX) n = NCAND_MAX;
    int m = KPRE;
    while (m < n) m <<= 1;
    int nq = m >> 10;
    for (int q = 0; q < nq; q++) {
        int s = t + (q << 10);
        keys[s] = (s < n) ? cand[(size_t)b * NCAND_MAX + s] : ~0ull;
    }
    __syncthreads();
    // ascending bitonic sort: key ascending = score descending, ties by ascending idx
    for (int k = 2; k <= m; k <<= 1) {
        for (int j = k >> 1; j > 0; j >>= 1) {
            for (int q = 0; q < nq; q++) {
                int i = t + (q << 10);
                int ixj = i ^ j;
                if (ixj > i) {
                    unsigned long long a = keys[i], bb = keys[ixj];
                    bool up = ((i & k) == 0);
                    if ((a > bb) == up) { keys[i] = bb; keys[ixj] = a; }
                }
            }
            __syncthreads();
        }
    }
    int o = (b << 10) + t;
    if (t < n) {
        unsigned long long key = keys[t];
        unsigned kk = (unsigned)(key >> 32);
        unsigned mm = ~kk;
        unsigned bits = (mm & 0x80000000u) ? (mm & 0x7FFFFFFFu) : ~mm;
        topconf[o] = __uint_as_float(bits);     // exact original score
        topidx[o] = (unsigned)(key & 0xFFFFFFFFu);
    } else {
        topconf[o] = -1.0f;
        topidx[o] = IDX_PAD;
    }
}

// ---------------- kernel 4b: exact argmax + box build for the 16K survivors only ----------------
__global__ __launch_bounds__(256) void argmax_gather(const float* __restrict__ x,
                                                     const unsigned* __restrict__ topidx,
                                                     float4* __restrict__ topbox,
                                                     float4* __restrict__ topoff,
                                                     float* __restrict__ topcls) {
#pragma clang fp contract(off)
    int gid = blockIdx.x * 256 + threadIdx.x;
    int o = gid >> 2;                           // entry in [0, BATCH*KPRE)
    int q = gid & 3;
    int b = o >> 10;
    unsigned idx = topidx[o];

    float4 box = make_float4(0.f, 0.f, 0.f, 0.f);
    float clsf = 0.f;
    if (idx != IDX_PAD) {
        size_t base = ((size_t)b * NBOX + idx) * NCH;
        float obj = x[base + 4];
        int cbase = 5 + q * 20;
        float v = -1e30f; int c = 0;
        #pragma unroll
        for (int j = 0; j < 20; j++) {
            float s = x[base + cbase + j] * obj;
            if (s > v) { v = s; c = q * 20 + j; }      // strict > = first occurrence
        }
        #pragma unroll
        for (int off = 1; off <= 2; off <<= 1) {
            float ov = __shfl_xor(v, off);
            int   oc = __shfl_xor(c, off);
            if (ov > v || (ov == v && oc < c)) { v = ov; c = oc; }
        }
        if (q == 0) {
            float cx = x[base + 0], cy = x[base + 1], w = x[base + 2], h = x[base + 3];
            box = make_float4(cx - w * 0.5f, cy - h * 0.5f, cx + w * 0.5f, cy + h * 0.5f);
            clsf = (float)c;
        }
    }
    if (q == 0) {
        topbox[o] = box;
        topcls[o] = clsf;
        float off = clsf * 4096.0f;
        topoff[o] = make_float4(box.x + off, box.y + off, box.z + off, box.w + off);
    }
}

// ---------------- kernel 5: pairwise IoU suppression bitmask + per-row summary ----------------
__global__ __launch_bounds__(256) void iou_mask(const float4* __restrict__ topoff,
                                                unsigned long long* __restrict__ mask,
                                                unsigned short* __restrict__ summ) {
#pragma clang fp contract(off)
    __shared__ float4 soff[KPRE];
    int b = blockIdx.x >> 6;
    int blk = blockIdx.x & 63;
    int t = threadIdx.x;
    for (int q = 0; q < 4; q++) {
        int s = t + q * 256;
        soff[s] = topoff[(b << 10) + s];
    }
    __syncthreads();
    int i = (blk << 4) + (t >> 4);
    int w = t & 15;
    unsigned long long bits = 0;
    int jbase = w << 6;
    if (jbase + 63 > i) {                       // lower-triangle words are identically 0
        float4 a = soff[i];
        float area_a = (a.z - a.x) * (a.w - a.y);
        for (int jj = 0; jj < 64; jj++) {
            int j = jbase + jj;
            float4 bb = soff[j];
            float area_b = (bb.z - bb.x) * (bb.w - bb.y);
            float ltx = fmaxf(a.x, bb.x), lty = fmaxf(a.y, bb.y);
            float rbx = fminf(a.z, bb.z), rby = fminf(a.w, bb.w);
            float wx = fmaxf(rbx - ltx, 0.0f), wy = fmaxf(rby - lty, 0.0f);
            float inter = wx * wy;
            float iou = inter / (area_a + area_b - inter + 1e-7f);
            if (j > i && iou > 0.45f) bits |= (1ull << jj);
        }
    }
    mask[((size_t)((b << 10) + i) << 4) + w] = bits;
    unsigned long long bal = __ballot(bits != 0ull);
    if (w == 0) {
        int l = t & 63;
        summ[(b << 10) + i] = (unsigned short)((bal >> ((l >> 4) << 4)) & 0xFFFFull);
    }
}

// ---------------- kernel 6: greedy suppression + ordered output (merged, 1 block / batch) ----------------
// Wave 0 runs the sparsity-driven greedy scan into LDS; whole block then compacts to dets.
__global__ __launch_bounds__(1024) void nms_finalize(const unsigned long long* __restrict__ mask,
                                                     const unsigned short* __restrict__ summ,
                                                     const float* __restrict__ topconf,
                                                     const float4* __restrict__ topbox,
                                                     const float* __restrict__ topcls,
                                                     float* __restrict__ dets,
                                                     float* __restrict__ vmask) {
    __shared__ unsigned long long kb[16];
    int b = blockIdx.x, tid = threadIdx.x;

    if (tid < 64) {
        int lane = tid;
        const unsigned long long* mrow = mask + ((size_t)b << 14);
        unsigned long long keep0[16];
        #pragma unroll
        for (int c = 0; c < 16; c++) {
            float cf = topconf[(b << 10) + (c << 6) + lane];
            keep0[c] = __ballot(cf > 0.0f);
        }
        unsigned nz[16];
        #pragma unroll
        for (int t = 0; t < 16; t++)
            nz[t] = (unsigned)summ[(b << 10) + (t << 6) + lane];
        unsigned long long diag[16];
        #pragma unroll
        for (int t = 0; t < 16; t++)
            diag[t] = mrow[((size_t)((t << 6) + lane) << 4) + t];

        unsigned long long remv[16];
        #pragma unroll
        for (int t = 0; t < 16; t++) remv[t] = 0;

        #pragma unroll
        for (int t = 0; t < 16; t++) {
            unsigned long long live = keep0[t] & ~remv[t];
            unsigned long long kept = live;
            unsigned long long pend = live & __ballot((nz[t] >> t) & 1u);
            while (pend) {
                int j = (int)__ffsll(pend) - 1;
                pend &= pend - 1;
                if ((kept >> j) & 1ull) {
                    unsigned long long dj = __shfl(diag[t], j);
                    kept &= ~dj;
                    pend &= ~dj;
                }
            }
            if (lane == 0) kb[t] = kept;

            #pragma unroll
            for (int w = 0; w < 16; w++) {
                if (w > t) {
                    unsigned long long wm = kept & __ballot((nz[t] >> w) & 1u);
                    while (wm) {
                        int j = (int)__ffsll(wm) - 1;
                        wm &= wm - 1;
                        remv[w] |= mrow[((size_t)((t << 6) + j) << 4) + w];
                    }
                }
            }
        }
    }
    __syncthreads();

    int r = tid;
    int w = r >> 6, l = r & 63;
    unsigned long long word = kb[w];
    int keep = (int)((word >> l) & 1ull);
    int base = 0, total = 0;
    #pragma unroll
    for (int q = 0; q < 16; q++) {
        int c = __popcll(kb[q]);
        total += c;
        if (q < w) base += c;
    }
    int rank = base + __popcll((l == 0) ? 0ull : (word & ((~0ull) >> (64 - l))));
    float* drow = dets + (size_t)b * (MAXDET * 6);
    float* vm = vmask + (size_t)b * MAXDET;
    if (r < MAXDET && r >= total) {
#pragma unroll
        for (int cc = 0; cc < 6; cc++) drow[r * 6 + cc] = 0.0f;
        vm[r] = 0.0f;
    }
    if (keep && rank < MAXDET) {
        int o = (b << 10) + r;
        float4 bx = topbox[o];
        drow[rank * 6 + 0] = bx.x;
        drow[rank * 6 + 1] = bx.y;
        drow[rank * 6 + 2] = bx.z;
        drow[rank * 6 + 3] = bx.w;
        drow[rank * 6 + 4] = topconf[o];
        drow[rank * 6 + 5] = topcls[o];
        vm[rank] = 1.0f;
    }
}

// ---------------- launcher ----------------
extern "C" void kernel_launch(void* const* d_in, const int* in_sizes, int n_in,
                              void* d_out, int out_size, void* d_ws, size_t ws_size,
                              hipStream_t stream) {
    const float* x = (const float*)d_in[0];
    char* w = (char*)d_ws;

    // fixed workspace layout (hist last, adaptively sized)
    unsigned long long* cand     = (unsigned long long*)(w + 0);        // 524288
    unsigned long long* mask     = (unsigned long long*)(w + 524288);   // 2097152
    unsigned*           k32      = (unsigned*)(w + 2623488);            // 1612800
    float4*             topbox   = (float4*)(w + 4236288);              // 262144
    float4*             topoff   = (float4*)(w + 4498432);              // 262144
    float*              topconf  = (float*)(w + 4760576);               // 65536
    float*              topcls   = (float*)(w + 4826112);               // 65536
    unsigned*           topidx   = (unsigned*)(w + 4891648);            // 65536
    unsigned*           cutoff   = (unsigned*)(w + 4957184);            // 64
    unsigned*           ncand    = (unsigned*)(w + 4957248);            // 64
    unsigned short*     summ     = (unsigned short*)(w + 4957312);      // 32768
    unsigned*           chunkCnt = (unsigned*)(w + 4990080);            // 6336
    unsigned*           hist     = (unsigned*)(w + 4996480);            // 16*hs*4

    // adaptive histogram resolution (finer = less atomic contention)
    int shift, hs;
    if (ws_size >= 4996480ull + (size_t)BATCH * 65536 * 4) { shift = 16; hs = 65536; }
    else if (ws_size >= 4996480ull + (size_t)BATCH * 16384 * 4) { shift = 18; hs = 16384; }
    else return;  // insufficient scratch -> deterministic failure

    int n16 = (BATCH * hs * 4) / 16;
    zero_kernel<<<(n16 + 255) / 256, 256, 0, stream>>>((uint4*)hist, n16);

    score_kernel<<<(BATCH * NBOX) / 64, 256, 0, stream>>>(x, k32, hist, shift, hs);
    select_cutoff<<<BATCH, 256, 0, stream>>>(hist, cutoff, hs);
    count_kernel<<<dim3(NCHUNK, BATCH), 256, 0, stream>>>(k32, cutoff, chunkCnt, shift);
    scan_kernel<<<BATCH, 128, 0, stream>>>(chunkCnt, ncand);
    place_kernel<<<dim3(NCHUNK, BATCH), 256, 0, stream>>>(k32, cutoff, chunkCnt, cand, shift);
    sort_gather<<<BATCH, 1024, 0, stream>>>(cand, ncand, topconf, topidx);
    argmax_gather<<<(BATCH * KPRE * 4) / 256, 256, 0, stream>>>(x, topidx, topbox, topoff, topcls);
    iou_mask<<<BATCH * 64, 256, 0, stream>>>(topoff, mask, summ);

    float* dets = (float*)d_out;
    float* vmask = dets + (size_t)BATCH * MAXDET * 6;
    nms_finalize<<<BATCH, 1024, 0, stream>>>(mask, summ, topconf, topbox, topcls, dets, vmask);
}

// Round 12
// 187.765 us; speedup vs baseline: 1.0863x; 1.0863x over previous
//
#include <hip/hip_runtime.h>
#include <cstdint>
#include <cstddef>

// ---------------- problem constants ----------------
#define BATCH 16
#define NBOX 25200
#define NCH 85          // 4 box + 1 obj + 80 cls
#define KPRE 1024
#define MAXDET 1000
#define NCAND_MAX 4096
#define HS 65536        // histogram buckets (key >> 16)
#define SHIFT 16
#define IDX_PAD 0xFFFFFFFFu

__device__ __forceinline__ unsigned key_of(float s) {
    // monotone map: larger score -> SMALLER key (ascending sort = descending score)
    unsigned u = __float_as_uint(s);
    unsigned m = (u & 0x80000000u) ? ~u : (u | 0x80000000u);
    return ~m;
}

// ---------------- kernel 0: fast workspace zero ----------------
__global__ __launch_bounds__(256) void zero_kernel(uint4* __restrict__ p, int n16) {
    int i = blockIdx.x * 256 + threadIdx.x;
    if (i < n16) p[i] = make_uint4(0u, 0u, 0u, 0u);
}

// ---------------- kernel 1: per-box max-product score + key + histogram ----------------
// (best measured variant: 2 lanes/box, 10 float4 loads, max-only, fine histogram)
__global__ __launch_bounds__(256, 2) void score_kernel(const float* __restrict__ x,
                                                       unsigned* __restrict__ k32,
                                                       unsigned* __restrict__ hist) {
    int gid = blockIdx.x * 256 + threadIdx.x;
    int box = gid >> 1;
    int q = gid & 1;
    size_t base = (size_t)box * NCH;

    float obj = x[base + 4];
    const float4* p = (const float4*)(x + base + 5 + q * 40);
    float4 r[10];
    #pragma unroll
    for (int j = 0; j < 10; j++) r[j] = p[j];   // 10 independent loads in flight

    float v = -1e30f;
    #pragma unroll
    for (int j = 0; j < 10; j++) {              // max of products; value order-invariant
        float m0 = fmaxf(r[j].x * obj, r[j].y * obj);
        float m1 = fmaxf(r[j].z * obj, r[j].w * obj);
        v = fmaxf(v, fmaxf(m0, m1));
    }
    v = fmaxf(v, __shfl_xor(v, 1));             // combine halves

    if (q == 0) {
        bool validb = (obj > 0.25f) && (v > 0.25f);
        float score = validb ? v : -1.0f;
        unsigned k = key_of(score);
        k32[box] = k;
        if (validb) {
            int b = box / NBOX;
            atomicAdd(&hist[b * HS + (int)(k >> SHIFT)], 1u);  // commutative -> deterministic
        }
    }
}

// ---------------- kernel 2: fused per-batch front tail (1 block / batch) ----------------
// cutoff -> deterministic compaction into LDS -> bitonic sort -> decode -> argmax+box.
__global__ __launch_bounds__(1024) void mega_front(const float* __restrict__ x,
                                                   const unsigned* __restrict__ k32,
                                                   const unsigned* __restrict__ hist,
                                                   float* __restrict__ topconf,
                                                   float4* __restrict__ topbox,
                                                   float4* __restrict__ topoff,
                                                   float* __restrict__ topcls) {
#pragma clang fp contract(off)
    __shared__ unsigned long long keys[NCAND_MAX];   // 32 KB
    __shared__ unsigned part[1024];
    __shared__ unsigned wsum[16];
    __shared__ unsigned wcnt[16];
    __shared__ unsigned cutP;
    int b = blockIdx.x, t = threadIdx.x;
    int lane = t & 63, wv = t >> 6;

    // ---- phase A: histogram cutoff covering rank KPRE ----
    const unsigned* h = hist + (size_t)b * HS;
    {
        const uint4* h4 = (const uint4*)(h + t * 64);
        unsigned s = 0;
        #pragma unroll
        for (int j = 0; j < 16; j++) { uint4 v4 = h4[j]; s += v4.x + v4.y + v4.z + v4.w; }
        part[t] = s;
        unsigned ws = s;
        #pragma unroll
        for (int off = 1; off < 64; off <<= 1) ws += __shfl_xor(ws, off);
        if (lane == 0) wsum[wv] = ws;
    }
    __syncthreads();
    if (t == 0) {
        unsigned cum = 0; int W = -1;
        for (int w = 0; w < 16; w++)
            if (W < 0) { if (cum + wsum[w] >= KPRE) W = w; else cum += wsum[w]; }
        int T = -1;
        if (W >= 0)
            for (int i = 0; i < 64; i++)
                if (T < 0) { int p = W * 64 + i; if (cum + part[p] >= KPRE) T = p; else cum += part[p]; }
        unsigned P = HS - 1;                     // fewer than KPRE valid -> take all valid
        if (T >= 0)
            for (int j = 0; j < 64; j++) { cum += h[T * 64 + j]; if (cum >= KPRE) { P = (unsigned)(T * 64 + j); break; } }
        cutP = P;
    }
    __syncthreads();
    unsigned P = cutP;

    // ---- phase B: deterministic index-ordered compaction into LDS ----
    const unsigned* kb = k32 + (size_t)b * NBOX;
    unsigned base = 0;                            // uniform across block
    for (int c = 0; c < 25; c++) {
        int i = c * 1024 + t;
        unsigned k = 0; bool pass = false;
        if (i < NBOX) { k = kb[i]; pass = ((int)k >= 0) && ((k >> SHIFT) <= P); }
        unsigned long long m = __ballot(pass);
        if (lane == 0) wcnt[wv] = (unsigned)__popcll(m);
        __syncthreads();
        unsigned wpre = 0, tot = 0;
        #pragma unroll
        for (int q2 = 0; q2 < 16; q2++) { unsigned cc = wcnt[q2]; if (q2 < wv) wpre += cc; tot += cc; }
        unsigned rank = base + wpre + (unsigned)__popcll(lane ? (m & ((~0ull) >> (64 - lane))) : 0ull);
        if (pass && rank < NCAND_MAX)
            keys[rank] = ((unsigned long long)k << 32) | (unsigned)i;
        base += tot;
        __syncthreads();                          // protect wcnt reuse next iter
    }
    int n = (int)base; if (n > NCAND_MAX) n = NCAND_MAX;
    int m2 = KPRE; while (m2 < n) m2 <<= 1;
    int nq = m2 >> 10;
    for (int q = 0; q < nq; q++) { int s2 = t + (q << 10); if (s2 >= n) keys[s2] = ~0ull; }
    __syncthreads();

    // ---- phase C: ascending bitonic sort (key asc = score desc, ties by asc idx) ----
    for (int k = 2; k <= m2; k <<= 1) {
        for (int j = k >> 1; j > 0; j >>= 1) {
            for (int q = 0; q < nq; q++) {
                int i = t + (q << 10);
                int ixj = i ^ j;
                if (ixj > i) {
                    unsigned long long a = keys[i], bb = keys[ixj];
                    bool up = ((i & k) == 0);
                    if ((a > bb) == up) { keys[i] = bb; keys[ixj] = a; }
                }
            }
            __syncthreads();
        }
    }

    // ---- phase D: decode rank t -> topconf ----
    int o = (b << 10) + t;
    {
        float conf = -1.0f;
        if (t < n) {
            unsigned kk = (unsigned)(keys[t] >> 32);
            unsigned mm = ~kk;
            unsigned bits = (mm & 0x80000000u) ? (mm & 0x7FFFFFFFu) : ~mm;
            conf = __uint_as_float(bits);          // exact original score
        }
        topconf[o] = conf;
    }

    // ---- phase E: exact argmax + box build for entry t ----
    unsigned idx = (t < n) ? (unsigned)(keys[t] & 0xFFFFFFFFu) : IDX_PAD;
    float4 box = make_float4(0.f, 0.f, 0.f, 0.f);
    float clsf = 0.f;
    if (idx != IDX_PAD) {
        size_t rb = ((size_t)b * NBOX + idx) * NCH;
        float obj = x[rb + 4];
        float v = -1e30f; int cbest = 0;
        #pragma unroll
        for (int hh = 0; hh < 2; hh++) {
            const float4* p4 = (const float4*)(x + rb + 5 + hh * 40);
            float4 rr[10];
            #pragma unroll
            for (int j = 0; j < 10; j++) rr[j] = p4[j];
            #pragma unroll
            for (int j = 0; j < 10; j++) {         // ascending class order, strict > = first occurrence
                float s0 = rr[j].x * obj; if (s0 > v) { v = s0; cbest = hh * 40 + j * 4 + 0; }
                float s1 = rr[j].y * obj; if (s1 > v) { v = s1; cbest = hh * 40 + j * 4 + 1; }
                float s2 = rr[j].z * obj; if (s2 > v) { v = s2; cbest = hh * 40 + j * 4 + 2; }
                float s3 = rr[j].w * obj; if (s3 > v) { v = s3; cbest = hh * 40 + j * 4 + 3; }
            }
        }
        float cx = x[rb + 0], cy = x[rb + 1], wd = x[rb + 2], ht = x[rb + 3];
        box = make_float4(cx - wd * 0.5f, cy - ht * 0.5f, cx + wd * 0.5f, cy + ht * 0.5f);
        clsf = (float)cbest;
    }
    topbox[o] = box;
    topcls[o] = clsf;
    float offv = clsf * 4096.0f;
    topoff[o] = make_float4(box.x + offv, box.y + offv, box.z + offv, box.w + offv);
}

// ---------------- kernel 3: pairwise IoU suppression bitmask + per-row summary ----------------
__global__ __launch_bounds__(256) void iou_mask(const float4* __restrict__ topoff,
                                                unsigned long long* __restrict__ mask,
                                                unsigned short* __restrict__ summ) {
#pragma clang fp contract(off)
    __shared__ float4 soff[KPRE];
    int b = blockIdx.x >> 6;
    int blk = blockIdx.x & 63;
    int t = threadIdx.x;
    for (int q = 0; q < 4; q++) {
        int s = t + q * 256;
        soff[s] = topoff[(b << 10) + s];
    }
    __syncthreads();
    int i = (blk << 4) + (t >> 4);
    int w = t & 15;
    unsigned long long bits = 0;
    int jbase = w << 6;
    if (jbase + 63 > i) {                       // lower-triangle words are identically 0
        float4 a = soff[i];
        float area_a = (a.z - a.x) * (a.w - a.y);
        for (int jj = 0; jj < 64; jj++) {
            int j = jbase + jj;
            float4 bb = soff[j];
            float area_b = (bb.z - bb.x) * (bb.w - bb.y);
            float ltx = fmaxf(a.x, bb.x), lty = fmaxf(a.y, bb.y);
            float rbx = fminf(a.z, bb.z), rby = fminf(a.w, bb.w);
            float wx = fmaxf(rbx - ltx, 0.0f), wy = fmaxf(rby - lty, 0.0f);
            float inter = wx * wy;
            float iou = inter / (area_a + area_b - inter + 1e-7f);
            if (j > i && iou > 0.45f) bits |= (1ull << jj);
        }
    }
    mask[((size_t)((b << 10) + i) << 4) + w] = bits;
    unsigned long long bal = __ballot(bits != 0ull);
    if (w == 0) {
        int l = t & 63;
        summ[(b << 10) + i] = (unsigned short)((bal >> ((l >> 4) << 4)) & 0xFFFFull);
    }
}

// ---------------- kernel 4: greedy suppression + ordered output (1 block / batch) ----------------
__global__ __launch_bounds__(1024) void nms_finalize(const unsigned long long* __restrict__ mask,
                                                     const unsigned short* __restrict__ summ,
                                                     const float* __restrict__ topconf,
                                                     const float4* __restrict__ topbox,
                                                     const float* __restrict__ topcls,
                                                     float* __restrict__ dets,
                                                     float* __restrict__ vmask) {
    __shared__ unsigned long long kb[16];
    int b = blockIdx.x, tid = threadIdx.x;

    if (tid < 64) {
        int lane = tid;
        const unsigned long long* mrow = mask + ((size_t)b << 14);
        unsigned long long keep0[16];
        #pragma unroll
        for (int c = 0; c < 16; c++) {
            float cf = topconf[(b << 10) + (c << 6) + lane];
            keep0[c] = __ballot(cf > 0.0f);
        }
        unsigned nz[16];
        #pragma unroll
        for (int t = 0; t < 16; t++)
            nz[t] = (unsigned)summ[(b << 10) + (t << 6) + lane];
        unsigned long long diag[16];
        #pragma unroll
        for (int t = 0; t < 16; t++)
            diag[t] = mrow[((size_t)((t << 6) + lane) << 4) + t];

        unsigned long long remv[16];
        #pragma unroll
        for (int t = 0; t < 16; t++) remv[t] = 0;

        #pragma unroll
        for (int t = 0; t < 16; t++) {
            unsigned long long live = keep0[t] & ~remv[t];
            unsigned long long kept = live;
            unsigned long long pend = live & __ballot((nz[t] >> t) & 1u);
            while (pend) {
                int j = (int)__ffsll(pend) - 1;
                pend &= pend - 1;
                if ((kept >> j) & 1ull) {
                    unsigned long long dj = __shfl(diag[t], j);
                    kept &= ~dj;
                    pend &= ~dj;
                }
            }
            if (lane == 0) kb[t] = kept;

            #pragma unroll
            for (int w = 0; w < 16; w++) {
                if (w > t) {
                    unsigned long long wm = kept & __ballot((nz[t] >> w) & 1u);
                    while (wm) {
                        int j = (int)__ffsll(wm) - 1;
                        wm &= wm - 1;
                        remv[w] |= mrow[((size_t)((t << 6) + j) << 4) + w];
                    }
                }
            }
        }
    }
    __syncthreads();

    int r = tid;
    int w = r >> 6, l = r & 63;
    unsigned long long word = kb[w];
    int keep = (int)((word >> l) & 1ull);
    int base = 0, total = 0;
    #pragma unroll
    for (int q = 0; q < 16; q++) {
        int c = __popcll(kb[q]);
        total += c;
        if (q < w) base += c;
    }
    int rank = base + __popcll((l == 0) ? 0ull : (word & ((~0ull) >> (64 - l))));
    float* drow = dets + (size_t)b * (MAXDET * 6);
    float* vm = vmask + (size_t)b * MAXDET;
    if (r < MAXDET && r >= total) {
#pragma unroll
        for (int cc = 0; cc < 6; cc++) drow[r * 6 + cc] = 0.0f;
        vm[r] = 0.0f;
    }
    if (keep && rank < MAXDET) {
        int o = (b << 10) + r;
        float4 bx = topbox[o];
        drow[rank * 6 + 0] = bx.x;
        drow[rank * 6 + 1] = bx.y;
        drow[rank * 6 + 2] = bx.z;
        drow[rank * 6 + 3] = bx.w;
        drow[rank * 6 + 4] = topconf[o];
        drow[rank * 6 + 5] = topcls[o];
        vm[rank] = 1.0f;
    }
}

// ---------------- launcher ----------------
extern "C" void kernel_launch(void* const* d_in, const int* in_sizes, int n_in,
                              void* d_out, int out_size, void* d_ws, size_t ws_size,
                              hipStream_t stream) {
    const float* x = (const float*)d_in[0];
    char* w = (char*)d_ws;

    // workspace layout (bytes), total 8,592,384
    unsigned long long* mask    = (unsigned long long*)(w + 0);        // 2,097,152
    unsigned*           k32     = (unsigned*)(w + 2097152);            // 1,612,800
    float4*             topbox  = (float4*)(w + 3709952);              // 262,144
    float4*             topoff  = (float4*)(w + 3972096);              // 262,144
    float*              topconf = (float*)(w + 4234240);               // 65,536
    float*              topcls  = (float*)(w + 4299776);               // 65,536
    unsigned short*     summ    = (unsigned short*)(w + 4365312);      // 32,768
    unsigned*           hist    = (unsigned*)(w + 4398080);            // 16*65536*4 = 4,194,304
    if (ws_size < 8592384) return;  // insufficient scratch -> deterministic failure

    int n16 = (BATCH * HS * 4) / 16;
    zero_kernel<<<(n16 + 255) / 256, 256, 0, stream>>>((uint4*)hist, n16);

    score_kernel<<<(BATCH * NBOX * 2) / 256, 256, 0, stream>>>(x, k32, hist);
    mega_front<<<BATCH, 1024, 0, stream>>>(x, k32, hist, topconf, topbox, topoff, topcls);
    iou_mask<<<BATCH * 64, 256, 0, stream>>>(topoff, mask, summ);

    float* dets = (float*)d_out;
    float* vmask = dets + (size_t)BATCH * MAXDET * 6;
    nms_finalize<<<BATCH, 1024, 0, stream>>>(mask, summ, topconf, topbox, topcls, dets, vmask);
}